// Round 1
// baseline (10065.992 us; speedup 1.0000x reference)
//
#include <hip/hip_runtime.h>

#define HEADS 4

// ---- monotonic float <-> uint mapping for atomicMax on floats ----
__device__ __forceinline__ unsigned fmap(float f) {
  unsigned u = __float_as_uint(f);
  return (u & 0x80000000u) ? ~u : (u | 0x80000000u);
}
__device__ __forceinline__ float funmap(unsigned m) {
  unsigned u = (m & 0x80000000u) ? (m ^ 0x80000000u) : ~m;
  return __uint_as_float(u);
}

// ---------- node GEMM: Y[N,M] = X[N,K] @ W[K,M] + b ----------
template <int K, int M>
__global__ __launch_bounds__(256) void node_gemm(
    const float* __restrict__ X, const float* __restrict__ W,
    const float* __restrict__ bias, float* __restrict__ Y) {
  constexpr int NPB = 16;           // nodes per block (20000 % 16 == 0)
  constexpr int COLS4 = M / 4;      // 64 or 128
  constexpr int NG = 256 / COLS4;   // node groups per block: 4 or 2
  constexpr int RPN = NPB / NG;     // rows per thread: 4 or 8
  __shared__ float xs[NPB * K];
  const int tid = threadIdx.x;
  const int n0 = blockIdx.x * NPB;
  {
    const float4* X4 = reinterpret_cast<const float4*>(X + (size_t)n0 * K);
    float4* xs4 = reinterpret_cast<float4*>(xs);
    for (int i = tid; i < NPB * K / 4; i += 256) xs4[i] = X4[i];
  }
  __syncthreads();
  const int c4 = (tid % COLS4) * 4;
  const int r0 = (tid / COLS4) * RPN;
  float acc[RPN][4];
#pragma unroll
  for (int r = 0; r < RPN; ++r)
#pragma unroll
    for (int q = 0; q < 4; ++q) acc[r][q] = 0.f;

  for (int k = 0; k < K; k += 4) {
    float xv[RPN][4];
#pragma unroll
    for (int r = 0; r < RPN; ++r)
      *reinterpret_cast<float4*>(xv[r]) =
          *reinterpret_cast<const float4*>(&xs[(r0 + r) * K + k]);
#pragma unroll
    for (int j = 0; j < 4; ++j) {
      float wv[4];
      *reinterpret_cast<float4*>(wv) =
          *reinterpret_cast<const float4*>(&W[(size_t)(k + j) * M + c4]);
#pragma unroll
      for (int r = 0; r < RPN; ++r)
#pragma unroll
        for (int q = 0; q < 4; ++q)
          acc[r][q] = fmaf(xv[r][j], wv[q], acc[r][q]);
    }
  }
  float bv[4];
  *reinterpret_cast<float4*>(bv) = *reinterpret_cast<const float4*>(&bias[c4]);
#pragma unroll
  for (int r = 0; r < RPN; ++r) {
    float o[4];
#pragma unroll
    for (int q = 0; q < 4; ++q) o[q] = acc[r][q] + bv[q];
    *reinterpret_cast<float4*>(&Y[(size_t)(n0 + r0 + r) * M + c4]) =
        *reinterpret_cast<float4*>(o);
  }
}

// ---------- edge logits: m = lrelu(xl[src]+xr[dst]+ea@We); logit = <m, att>; atomicMax lmax ----------
template <int HC>
__global__ __launch_bounds__(256) void edge_logits(
    const float* __restrict__ xl, const float* __restrict__ xr,
    const float* __restrict__ ea, const float* __restrict__ We,
    const float* __restrict__ att, const int* __restrict__ ei,
    float* __restrict__ logits, unsigned* __restrict__ lmax, int E) {
  constexpr int C = HC / HEADS;
  constexpr int NCH = HC / 256;  // float4-chunks of 256 cols per lane
  const int lane = threadIdx.x & 63;
  const int wid = (blockIdx.x * blockDim.x + threadIdx.x) >> 6;
  const int nw = (gridDim.x * blockDim.x) >> 6;

  // We chunk held in registers: wef[k][ch][4] = We[k][ch*256 + lane*4 + j]
  float wef[16][NCH][4];
#pragma unroll
  for (int k = 0; k < 16; ++k)
#pragma unroll
    for (int ch = 0; ch < NCH; ++ch)
      *reinterpret_cast<float4*>(wef[k][ch]) =
          *reinterpret_cast<const float4*>(&We[k * HC + ch * 256 + lane * 4]);
  float attv[NCH][4];
#pragma unroll
  for (int ch = 0; ch < NCH; ++ch) {
    int c = ch * 256 + lane * 4;
    int h = c / C;
    *reinterpret_cast<float4*>(attv[ch]) =
        *reinterpret_cast<const float4*>(&att[h * C + (c % C)]);
  }
  const float4* xl4 = reinterpret_cast<const float4*>(xl);
  const float4* xr4 = reinterpret_cast<const float4*>(xr);

  for (int e = wid; e < E; e += nw) {
    const int src = ei[e], dst = ei[E + e];
    const float eav = ea[(size_t)e * 16 + (lane & 15)];
    float m[NCH][4];
#pragma unroll
    for (int ch = 0; ch < NCH; ++ch) {
      float4 a = xl4[(size_t)src * (HC / 4) + ch * 64 + lane];
      float4 b = xr4[(size_t)dst * (HC / 4) + ch * 64 + lane];
      m[ch][0] = a.x + b.x; m[ch][1] = a.y + b.y;
      m[ch][2] = a.z + b.z; m[ch][3] = a.w + b.w;
    }
#pragma unroll
    for (int k = 0; k < 16; ++k) {
      float a = __shfl(eav, k);  // lane k (0..15) holds ea[e][k]
#pragma unroll
      for (int ch = 0; ch < NCH; ++ch)
#pragma unroll
        for (int j = 0; j < 4; ++j) m[ch][j] = fmaf(a, wef[k][ch][j], m[ch][j]);
    }
    float part[NCH];
#pragma unroll
    for (int ch = 0; ch < NCH; ++ch) {
      float s = 0.f;
#pragma unroll
      for (int j = 0; j < 4; ++j) {
        float v = m[ch][j];
        v = (v >= 0.f) ? v : 0.2f * v;
        s = fmaf(v, attv[ch][j], s);
      }
      part[ch] = s;
    }
    if constexpr (HC == 256) {
      // 16 lanes per head
#pragma unroll
      for (int off = 1; off <= 8; off <<= 1) part[0] += __shfl_xor(part[0], off);
      if ((lane & 15) == 0) {
        int h = lane >> 4;
        logits[(size_t)e * 4 + h] = part[0];
        atomicMax(&lmax[(size_t)dst * 4 + h], fmap(part[0]));
      }
    } else {
      // 32 lanes per head; chunk0 -> heads 0/1, chunk1 -> heads 2/3
#pragma unroll
      for (int off = 1; off <= 16; off <<= 1) {
        part[0] += __shfl_xor(part[0], off);
        part[1] += __shfl_xor(part[1], off);
      }
      if ((lane & 31) == 0) {
        int h0 = lane >> 5;
        int h1 = 2 + (lane >> 5);
        logits[(size_t)e * 4 + h0] = part[0];
        atomicMax(&lmax[(size_t)dst * 4 + h0], fmap(part[0]));
        logits[(size_t)e * 4 + h1] = part[1];
        atomicMax(&lmax[(size_t)dst * 4 + h1], fmap(part[1]));
      }
    }
  }
}

// ---------- softmax numerator + denominator ----------
__global__ __launch_bounds__(256) void edge_softmax(
    const int* __restrict__ ei, const unsigned* __restrict__ lmax,
    float* __restrict__ lp, float* __restrict__ denom, int E) {
  int total = E * 4;
  for (int idx = blockIdx.x * blockDim.x + threadIdx.x; idx < total;
       idx += gridDim.x * blockDim.x) {
    int e = idx >> 2, hh = idx & 3;
    int dst = ei[E + e];
    float mx = funmap(lmax[(size_t)dst * 4 + hh]);
    float pv = __expf(lp[idx] - mx);
    lp[idx] = pv;
    atomicAdd(&denom[(size_t)dst * 4 + hh], pv);
  }
}

// ---------- weighted scatter: acc[dst] += alpha * xl[src] ----------
template <int HC>
__global__ __launch_bounds__(256) void edge_scatter(
    const float* __restrict__ xl, const float* __restrict__ p,
    const float* __restrict__ denom, const int* __restrict__ ei,
    float* __restrict__ acc, int E) {
  constexpr int C = HC / HEADS;
  constexpr int NCH = HC / 256;
  const int lane = threadIdx.x & 63;
  const int wid = (blockIdx.x * blockDim.x + threadIdx.x) >> 6;
  const int nw = (gridDim.x * blockDim.x) >> 6;
  const float4* xl4 = reinterpret_cast<const float4*>(xl);
  for (int e = wid; e < E; e += nw) {
    const int src = ei[e], dst = ei[E + e];
    float alpha[NCH];
#pragma unroll
    for (int ch = 0; ch < NCH; ++ch) {
      int h = (ch * 256 + lane * 4) / C;
      alpha[ch] = p[(size_t)e * 4 + h] / (denom[(size_t)dst * 4 + h] + 1e-16f);
    }
#pragma unroll
    for (int ch = 0; ch < NCH; ++ch) {
      float4 v = xl4[(size_t)src * (HC / 4) + ch * 64 + lane];
      float* ap = &acc[(size_t)dst * HC + ch * 256 + lane * 4];
      atomicAdd(ap + 0, alpha[ch] * v.x);
      atomicAdd(ap + 1, alpha[ch] * v.y);
      atomicAdd(ap + 2, alpha[ch] * v.z);
      atomicAdd(ap + 3, alpha[ch] * v.w);
    }
  }
}

// ---------- epilogues ----------
__global__ void add_bias(const float* __restrict__ acc, const float* __restrict__ bias,
                         float* __restrict__ out, int total, int M) {
  int idx = blockIdx.x * blockDim.x + threadIdx.x;
  if (idx < total) out[idx] = acc[idx] + bias[idx & (M - 1)];
}

__global__ void mean_heads(const float* __restrict__ acc, const float* __restrict__ bias,
                           float* __restrict__ out, int N) {
  int idx = blockIdx.x * blockDim.x + threadIdx.x;
  if (idx >= N * 128) return;
  int n = idx >> 7, c = idx & 127;
  const float* a = acc + (size_t)n * 512;
  out[idx] = 0.25f * (a[c] + a[128 + c] + a[256 + c] + a[384 + c]) + bias[c];
}

// ---------- pooling ----------
__global__ void pool_scatter(const float* __restrict__ h, const int* __restrict__ batch,
                             unsigned* __restrict__ pmax, float* __restrict__ psum,
                             float* __restrict__ cnt, int N) {
  int idx = blockIdx.x * blockDim.x + threadIdx.x;
  if (idx >= N * 128) return;
  int n = idx >> 7, c = idx & 127;
  int g = batch[n];
  float v = h[idx];
  atomicMax(&pmax[g * 128 + c], fmap(v));
  atomicAdd(&psum[g * 128 + c], v);
  if (c == 0) atomicAdd(&cnt[g], 1.f);
}

__global__ void pool_final(const unsigned* __restrict__ pmax, const float* __restrict__ psum,
                           const float* __restrict__ cnt, float* __restrict__ out) {
  int idx = blockIdx.x * blockDim.x + threadIdx.x;
  if (idx >= 64 * 128) return;
  int g = idx >> 7, c = idx & 127;
  float cg = cnt[g];
  out[g * 256 + c] = (cg > 0.f) ? funmap(pmax[idx]) : 0.f;
  out[g * 256 + 128 + c] = psum[idx] / fmaxf(cg, 1.f);
}

extern "C" void kernel_launch(void* const* d_in, const int* in_sizes, int n_in,
                              void* d_out, int out_size, void* d_ws, size_t ws_size,
                              hipStream_t stream) {
  const float* x     = (const float*)d_in[0];
  const float* ea    = (const float*)d_in[1];
  const int*   ei    = (const int*)d_in[2];
  const int*   batch = (const int*)d_in[3];
  const int N = in_sizes[0] / 128;  // 20000
  const int E = in_sizes[2] / 2;    // 640000

  const float* Wl[3]   = {(const float*)d_in[4],  (const float*)d_in[11], (const float*)d_in[18]};
  const float* blv[3]  = {(const float*)d_in[5],  (const float*)d_in[12], (const float*)d_in[19]};
  const float* Wr[3]   = {(const float*)d_in[6],  (const float*)d_in[13], (const float*)d_in[20]};
  const float* brv[3]  = {(const float*)d_in[7],  (const float*)d_in[14], (const float*)d_in[21]};
  const float* Wev[3]  = {(const float*)d_in[8],  (const float*)d_in[15], (const float*)d_in[22]};
  const float* attv[3] = {(const float*)d_in[9],  (const float*)d_in[16], (const float*)d_in[23]};
  const float* bias[3] = {(const float*)d_in[10], (const float*)d_in[17], (const float*)d_in[24]};

  // workspace layout (floats): ~154 MB total
  float* ws = (float*)d_ws;
  float* xl = ws;                              // N*512
  float* xr = xl + (size_t)N * 512;            // N*512
  float* acc = xr + (size_t)N * 512;           // N*512
  float* h = acc + (size_t)N * 512;            // N*256
  float* logits = h + (size_t)N * 256;         // E*4 (logits, then p in-place)
  unsigned* lmax = (unsigned*)(logits + (size_t)E * 4);  // N*4
  float* denom = (float*)(lmax + (size_t)N * 4);         // N*4
  unsigned* pmax = (unsigned*)(denom + (size_t)N * 4);   // 64*128
  float* psum = (float*)(pmax + 64 * 128);               // 64*128
  float* cnt = psum + 64 * 128;                          // 64

  const int nodeBlocks = N / 16;  // 1250
  const int eh_blocks = (E * 4 + 4096 * 256 - 1);  // (unused helper)
  (void)eh_blocks; (void)n_in; (void)out_size; (void)ws_size;

  // ================= layer 0 (K=128 -> hc=256, concat) =================
  node_gemm<128, 256><<<nodeBlocks, 256, 0, stream>>>(x, Wl[0], blv[0], xl);
  node_gemm<128, 256><<<nodeBlocks, 256, 0, stream>>>(x, Wr[0], brv[0], xr);
  hipMemsetAsync(lmax, 0, (size_t)N * 8 * sizeof(float), stream);  // lmax + denom
  hipMemsetAsync(acc, 0, (size_t)N * 256 * sizeof(float), stream);
  edge_logits<256><<<2048, 256, 0, stream>>>(xl, xr, ea, Wev[0], attv[0], ei, logits, lmax, E);
  edge_softmax<<<4096, 256, 0, stream>>>(ei, lmax, logits, denom, E);
  edge_scatter<256><<<2048, 256, 0, stream>>>(xl, logits, denom, ei, acc, E);
  add_bias<<<(N * 256 + 255) / 256, 256, 0, stream>>>(acc, bias[0], h, N * 256, 256);

  // ================= layer 1 (K=256 -> hc=256, concat) =================
  node_gemm<256, 256><<<nodeBlocks, 256, 0, stream>>>(h, Wl[1], blv[1], xl);
  node_gemm<256, 256><<<nodeBlocks, 256, 0, stream>>>(h, Wr[1], brv[1], xr);
  hipMemsetAsync(lmax, 0, (size_t)N * 8 * sizeof(float), stream);
  hipMemsetAsync(acc, 0, (size_t)N * 256 * sizeof(float), stream);
  edge_logits<256><<<2048, 256, 0, stream>>>(xl, xr, ea, Wev[1], attv[1], ei, logits, lmax, E);
  edge_softmax<<<4096, 256, 0, stream>>>(ei, lmax, logits, denom, E);
  edge_scatter<256><<<2048, 256, 0, stream>>>(xl, logits, denom, ei, acc, E);
  add_bias<<<(N * 256 + 255) / 256, 256, 0, stream>>>(acc, bias[1], h, N * 256, 256);

  // ================= layer 2 (K=256 -> hc=512, mean over heads) =================
  node_gemm<256, 512><<<nodeBlocks, 256, 0, stream>>>(h, Wl[2], blv[2], xl);
  node_gemm<256, 512><<<nodeBlocks, 256, 0, stream>>>(h, Wr[2], brv[2], xr);
  hipMemsetAsync(lmax, 0, (size_t)N * 8 * sizeof(float), stream);
  hipMemsetAsync(acc, 0, (size_t)N * 512 * sizeof(float), stream);
  edge_logits<512><<<2048, 256, 0, stream>>>(xl, xr, ea, Wev[2], attv[2], ei, logits, lmax, E);
  edge_softmax<<<4096, 256, 0, stream>>>(ei, lmax, logits, denom, E);
  edge_scatter<512><<<2048, 256, 0, stream>>>(xl, logits, denom, ei, acc, E);
  mean_heads<<<(N * 128 + 255) / 256, 256, 0, stream>>>(acc, bias[2], h, N);

  // ================= pooling =================
  hipMemsetAsync(pmax, 0, (size_t)(64 * 128 * 2 + 64) * sizeof(float), stream);
  pool_scatter<<<(N * 128 + 255) / 256, 256, 0, stream>>>(h, batch, pmax, psum, cnt, N);
  pool_final<<<(64 * 128 + 255) / 256, 256, 0, stream>>>(pmax, psum, cnt, (float*)d_out);
}

// Round 2
// 1760.661 us; speedup vs baseline: 5.7172x; 5.7172x over previous
//
#include <hip/hip_runtime.h>

#define HEADS 4

// ---- monotonic float <-> uint mapping for atomicMax on floats ----
__device__ __forceinline__ unsigned fmap(float f) {
  unsigned u = __float_as_uint(f);
  return (u & 0x80000000u) ? ~u : (u | 0x80000000u);
}
__device__ __forceinline__ float funmap(unsigned m) {
  unsigned u = (m & 0x80000000u) ? (m ^ 0x80000000u) : ~m;
  return __uint_as_float(u);
}

// ---------- node GEMM: Y[N,M] = X[N,K] @ W[K,M] + b ----------
template <int K, int M>
__global__ __launch_bounds__(256) void node_gemm(
    const float* __restrict__ X, const float* __restrict__ W,
    const float* __restrict__ bias, float* __restrict__ Y) {
  constexpr int NPB = 16;           // nodes per block (20000 % 16 == 0)
  constexpr int COLS4 = M / 4;      // 64 or 128
  constexpr int NG = 256 / COLS4;   // node groups per block: 4 or 2
  constexpr int RPN = NPB / NG;     // rows per thread: 4 or 8
  __shared__ float xs[NPB * K];
  const int tid = threadIdx.x;
  const int n0 = blockIdx.x * NPB;
  {
    const float4* X4 = reinterpret_cast<const float4*>(X + (size_t)n0 * K);
    float4* xs4 = reinterpret_cast<float4*>(xs);
    for (int i = tid; i < NPB * K / 4; i += 256) xs4[i] = X4[i];
  }
  __syncthreads();
  const int c4 = (tid % COLS4) * 4;
  const int r0 = (tid / COLS4) * RPN;
  float acc[RPN][4];
#pragma unroll
  for (int r = 0; r < RPN; ++r)
#pragma unroll
    for (int q = 0; q < 4; ++q) acc[r][q] = 0.f;

  for (int k = 0; k < K; k += 4) {
    float xv[RPN][4];
#pragma unroll
    for (int r = 0; r < RPN; ++r)
      *reinterpret_cast<float4*>(xv[r]) =
          *reinterpret_cast<const float4*>(&xs[(r0 + r) * K + k]);
#pragma unroll
    for (int j = 0; j < 4; ++j) {
      float wv[4];
      *reinterpret_cast<float4*>(wv) =
          *reinterpret_cast<const float4*>(&W[(size_t)(k + j) * M + c4]);
#pragma unroll
      for (int r = 0; r < RPN; ++r)
#pragma unroll
        for (int q = 0; q < 4; ++q)
          acc[r][q] = fmaf(xv[r][j], wv[q], acc[r][q]);
    }
  }
  float bv[4];
  *reinterpret_cast<float4*>(bv) = *reinterpret_cast<const float4*>(&bias[c4]);
#pragma unroll
  for (int r = 0; r < RPN; ++r) {
    float o[4];
#pragma unroll
    for (int q = 0; q < 4; ++q) o[q] = acc[r][q] + bv[q];
    *reinterpret_cast<float4*>(&Y[(size_t)(n0 + r0 + r) * M + c4]) =
        *reinterpret_cast<float4*>(o);
  }
}

// ---------- CSR build ----------
__global__ void edge_hist(const int* __restrict__ ei, int* __restrict__ deg, int E) {
  int i = blockIdx.x * blockDim.x + threadIdx.x;
  if (i < E) atomicAdd(&deg[ei[E + i]], 1);
}

__global__ __launch_bounds__(1024) void scan_rowptr(const int* __restrict__ deg,
                                                    int* __restrict__ rowptr, int N) {
  __shared__ int buf[1024];
  __shared__ int carry_s;
  const int tid = threadIdx.x;
  if (tid == 0) { carry_s = 0; rowptr[0] = 0; }
  __syncthreads();
  for (int base = 0; base < N; base += 1024) {
    int v = (base + tid < N) ? deg[base + tid] : 0;
    buf[tid] = v;
    __syncthreads();
    for (int off = 1; off < 1024; off <<= 1) {
      int t = (tid >= off) ? buf[tid - off] : 0;
      __syncthreads();
      buf[tid] += t;
      __syncthreads();
    }
    if (base + tid < N) rowptr[base + tid + 1] = carry_s + buf[tid];
    __syncthreads();
    if (tid == 0) carry_s += buf[1023];
    __syncthreads();
  }
}

__global__ void csr_fill(const int* __restrict__ ei, const int* __restrict__ rowptr,
                         int* __restrict__ fillc, int* __restrict__ csr_src,
                         int* __restrict__ csr_eid, int E) {
  int i = blockIdx.x * blockDim.x + threadIdx.x;
  if (i < E) {
    int d = ei[E + i];
    int pos = rowptr[d] + atomicAdd(&fillc[d], 1);
    csr_src[pos] = ei[i];
    csr_eid[pos] = i;
  }
}

// ---------- fused per-dst GATv2: logits + online softmax + aggregate ----------
// One wave owns (dst, 256-column group). No atomics.
template <int HC, bool CONCAT>
__global__ __launch_bounds__(256) void fused_gat(
    const float* __restrict__ xl, const float* __restrict__ xr,
    const float* __restrict__ ea, const float* __restrict__ We,
    const float* __restrict__ att, const float* __restrict__ bias,
    const int* __restrict__ rowptr, const int* __restrict__ csr_src,
    const int* __restrict__ csr_eid, float* __restrict__ out, int N) {
  constexpr int WPD = HC / 256;  // waves per dst
  constexpr int NH = 4 / WPD;    // heads handled by this wave
  constexpr int GS = 64 / NH;    // lanes per head group (16 or 32)
  constexpr int C = HC / 4;      // per-head dim
  const int tid = threadIdx.x;
  const int lane = tid & 63;
  const int wslot = tid >> 6;
  const int gw = blockIdx.x * 4 + wslot;
  const int dst = gw / WPD;
  const int cg = gw % WPD;
  __shared__ float lg[4][64][NH];
  if (dst >= N) return;

  // We fragment in registers: wef[k][q] = We[k][cg*256 + lane*4 + q]
  float wef[16][4];
#pragma unroll
  for (int k = 0; k < 16; ++k)
    *reinterpret_cast<float4*>(wef[k]) =
        *reinterpret_cast<const float4*>(&We[k * HC + cg * 256 + lane * 4]);
  const int col0 = cg * 256 + lane * 4;
  const int head = col0 / C;
  const int lh = (NH == 4) ? head : (lane >> 5);  // local head slot in lg
  float attv[4];
  *reinterpret_cast<float4*>(attv) =
      *reinterpret_cast<const float4*>(&att[head * C + (col0 % C)]);
  const float4* xl4 = reinterpret_cast<const float4*>(xl);
  const float4 xrv =
      reinterpret_cast<const float4*>(xr)[(size_t)dst * (HC / 4) + cg * 64 + lane];

  const int row0 = rowptr[dst];
  const int deg = rowptr[dst + 1] - row0;

  float m[NH], s[NH];
#pragma unroll
  for (int t = 0; t < NH; ++t) { m[t] = -__builtin_inff(); s[t] = 0.f; }
  float acc[4] = {0.f, 0.f, 0.f, 0.f};

  for (int cs = 0; cs < deg; cs += 64) {
    const int cn = min(64, deg - cs);
    const int srcv = (lane < cn) ? csr_src[row0 + cs + lane] : 0;
    const int eidv = (lane < cn) ? csr_eid[row0 + cs + lane] : 0;

    // ---- phase A: per-edge logits for this chunk ----
    for (int j = 0; j < cn; ++j) {
      const int src = __shfl(srcv, j);
      const int eid = __shfl(eidv, j);
      const float eav = ea[(size_t)eid * 16 + (lane & 15)];
      float4 a = xl4[(size_t)src * (HC / 4) + cg * 64 + lane];
      float mv[4] = {a.x + xrv.x, a.y + xrv.y, a.z + xrv.z, a.w + xrv.w};
#pragma unroll
      for (int k = 0; k < 16; ++k) {
        const float c = __shfl(eav, k);
#pragma unroll
        for (int q = 0; q < 4; ++q) mv[q] = fmaf(c, wef[k][q], mv[q]);
      }
      float p = 0.f;
#pragma unroll
      for (int q = 0; q < 4; ++q) {
        float v = mv[q];
        v = (v >= 0.f) ? v : 0.2f * v;
        p = fmaf(v, attv[q], p);
      }
#pragma unroll
      for (int off = 1; off < GS; off <<= 1) p += __shfl_xor(p, off);
      if ((lane & (GS - 1)) == 0) lg[wslot][j][lane / GS] = p;
    }

    // ---- online-softmax chunk reduction ----
    float cm[NH];
#pragma unroll
    for (int t = 0; t < NH; ++t) cm[t] = -__builtin_inff();
    if (lane < cn) {
#pragma unroll
      for (int t = 0; t < NH; ++t) cm[t] = lg[wslot][lane][t];
    }
#pragma unroll
    for (int off = 1; off < 64; off <<= 1)
#pragma unroll
      for (int t = 0; t < NH; ++t) cm[t] = fmaxf(cm[t], __shfl_xor(cm[t], off));
    float fh[NH];
#pragma unroll
    for (int t = 0; t < NH; ++t) {
      const float nm = fmaxf(m[t], cm[t]);
      fh[t] = __expf(m[t] - nm);  // m=-inf on first chunk -> 0
      m[t] = nm;
      s[t] *= fh[t];
    }
    const float fa = fh[lh];
#pragma unroll
    for (int q = 0; q < 4; ++q) acc[q] *= fa;

    float ps[NH];
#pragma unroll
    for (int t = 0; t < NH; ++t) ps[t] = 0.f;
    if (lane < cn) {
#pragma unroll
      for (int t = 0; t < NH; ++t) {
        const float p = __expf(lg[wslot][lane][t] - m[t]);
        lg[wslot][lane][t] = p;
        ps[t] = p;
      }
    }
#pragma unroll
    for (int off = 1; off < 64; off <<= 1)
#pragma unroll
      for (int t = 0; t < NH; ++t) ps[t] += __shfl_xor(ps[t], off);
#pragma unroll
    for (int t = 0; t < NH; ++t) s[t] += ps[t];

    // ---- phase B: weighted aggregation ----
    for (int j = 0; j < cn; ++j) {
      const int src = __shfl(srcv, j);
      const float pj = lg[wslot][j][lh];
      float4 v = xl4[(size_t)src * (HC / 4) + cg * 64 + lane];
      acc[0] = fmaf(pj, v.x, acc[0]);
      acc[1] = fmaf(pj, v.y, acc[1]);
      acc[2] = fmaf(pj, v.z, acc[2]);
      acc[3] = fmaf(pj, v.w, acc[3]);
    }
  }

  const float inv = 1.f / (s[lh] + 1e-16f);
  float o[4];
  if (CONCAT) {
    float bv[4];
    *reinterpret_cast<float4*>(bv) = *reinterpret_cast<const float4*>(&bias[col0]);
#pragma unroll
    for (int q = 0; q < 4; ++q) o[q] = acc[q] * inv + bv[q];
  } else {
#pragma unroll
    for (int q = 0; q < 4; ++q) o[q] = acc[q] * inv;
  }
  *reinterpret_cast<float4*>(&out[(size_t)dst * HC + col0]) =
      *reinterpret_cast<float4*>(o);
}

// ---------- layer-2 epilogue: mean over heads + bias ----------
__global__ void mean_heads(const float* __restrict__ acc, const float* __restrict__ bias,
                           float* __restrict__ out, int N) {
  int idx = blockIdx.x * blockDim.x + threadIdx.x;
  if (idx >= N * 128) return;
  int n = idx >> 7, c = idx & 127;
  const float* a = acc + (size_t)n * 512;
  out[idx] = 0.25f * (a[c] + a[128 + c] + a[256 + c] + a[384 + c]) + bias[c];
}

// ---------- pooling ----------
__global__ void pool_scatter(const float* __restrict__ h, const int* __restrict__ batch,
                             unsigned* __restrict__ pmax, float* __restrict__ psum,
                             float* __restrict__ cnt, int N) {
  int idx = blockIdx.x * blockDim.x + threadIdx.x;
  if (idx >= N * 128) return;
  int n = idx >> 7, c = idx & 127;
  int g = batch[n];
  float v = h[idx];
  atomicMax(&pmax[g * 128 + c], fmap(v));
  atomicAdd(&psum[g * 128 + c], v);
  if (c == 0) atomicAdd(&cnt[g], 1.f);
}

__global__ void pool_final(const unsigned* __restrict__ pmax, const float* __restrict__ psum,
                           const float* __restrict__ cnt, float* __restrict__ out) {
  int idx = blockIdx.x * blockDim.x + threadIdx.x;
  if (idx >= 64 * 128) return;
  int g = idx >> 7, c = idx & 127;
  float cg = cnt[g];
  out[g * 256 + c] = (cg > 0.f) ? funmap(pmax[idx]) : 0.f;
  out[g * 256 + 128 + c] = psum[idx] / fmaxf(cg, 1.f);
}

extern "C" void kernel_launch(void* const* d_in, const int* in_sizes, int n_in,
                              void* d_out, int out_size, void* d_ws, size_t ws_size,
                              hipStream_t stream) {
  const float* x     = (const float*)d_in[0];
  const float* ea    = (const float*)d_in[1];
  const int*   ei    = (const int*)d_in[2];
  const int*   batch = (const int*)d_in[3];
  const int N = in_sizes[0] / 128;  // 20000
  const int E = in_sizes[2] / 2;    // 640000

  const float* Wl[3]   = {(const float*)d_in[4],  (const float*)d_in[11], (const float*)d_in[18]};
  const float* blv[3]  = {(const float*)d_in[5],  (const float*)d_in[12], (const float*)d_in[19]};
  const float* Wr[3]   = {(const float*)d_in[6],  (const float*)d_in[13], (const float*)d_in[20]};
  const float* brv[3]  = {(const float*)d_in[7],  (const float*)d_in[14], (const float*)d_in[21]};
  const float* Wev[3]  = {(const float*)d_in[8],  (const float*)d_in[15], (const float*)d_in[22]};
  const float* attv[3] = {(const float*)d_in[9],  (const float*)d_in[16], (const float*)d_in[23]};
  const float* bias[3] = {(const float*)d_in[10], (const float*)d_in[17], (const float*)d_in[24]};

  // workspace layout
  float* ws = (float*)d_ws;
  float* xl   = ws;                            // N*512
  float* xr   = xl + (size_t)N * 512;          // N*512
  float* accb = xr + (size_t)N * 512;          // N*512 (layer-2 pre-mean)
  float* h    = accb + (size_t)N * 512;        // N*256
  int* rowptr = (int*)(h + (size_t)N * 256);   // N+1
  int* deg    = rowptr + (N + 1);              // N
  int* fillc  = deg + N;                       // N
  int* csr_src = fillc + N;                    // E
  int* csr_eid = csr_src + E;                  // E
  unsigned* pmax = (unsigned*)(csr_eid + E);   // 64*128
  float* psum = (float*)(pmax + 64 * 128);     // 64*128
  float* cnt  = psum + 64 * 128;               // 64
  (void)n_in; (void)out_size; (void)ws_size;

  const int nodeBlocks = N / 16;       // 1250
  const int edgeBlocks = (E + 255) / 256;

  // ---- CSR build (by destination) ----
  hipMemsetAsync(deg, 0, (size_t)2 * N * sizeof(int), stream);  // deg + fillc
  edge_hist<<<edgeBlocks, 256, 0, stream>>>(ei, deg, E);
  scan_rowptr<<<1, 1024, 0, stream>>>(deg, rowptr, N);
  csr_fill<<<edgeBlocks, 256, 0, stream>>>(ei, rowptr, fillc, csr_src, csr_eid, E);

  // ================= layer 0 (K=128 -> hc=256, concat) =================
  node_gemm<128, 256><<<nodeBlocks, 256, 0, stream>>>(x, Wl[0], blv[0], xl);
  node_gemm<128, 256><<<nodeBlocks, 256, 0, stream>>>(x, Wr[0], brv[0], xr);
  fused_gat<256, true><<<N / 4, 256, 0, stream>>>(
      xl, xr, ea, Wev[0], attv[0], bias[0], rowptr, csr_src, csr_eid, h, N);

  // ================= layer 1 (K=256 -> hc=256, concat) =================
  node_gemm<256, 256><<<nodeBlocks, 256, 0, stream>>>(h, Wl[1], blv[1], xl);
  node_gemm<256, 256><<<nodeBlocks, 256, 0, stream>>>(h, Wr[1], brv[1], xr);
  fused_gat<256, true><<<N / 4, 256, 0, stream>>>(
      xl, xr, ea, Wev[1], attv[1], bias[1], rowptr, csr_src, csr_eid, h, N);

  // ================= layer 2 (K=256 -> hc=512, mean over heads) =================
  node_gemm<256, 512><<<nodeBlocks, 256, 0, stream>>>(h, Wl[2], blv[2], xl);
  node_gemm<256, 512><<<nodeBlocks, 256, 0, stream>>>(h, Wr[2], brv[2], xr);
  fused_gat<512, false><<<N * 2 / 4, 256, 0, stream>>>(
      xl, xr, ea, Wev[2], attv[2], bias[2], rowptr, csr_src, csr_eid, accb, N);
  mean_heads<<<(N * 128 + 255) / 256, 256, 0, stream>>>(accb, bias[2], h, N);

  // ================= pooling =================
  hipMemsetAsync(pmax, 0, (size_t)(64 * 128 * 2 + 64) * sizeof(float), stream);
  pool_scatter<<<(N * 128 + 255) / 256, 256, 0, stream>>>(h, batch, pmax, psum, cnt, N);
  pool_final<<<(64 * 128 + 255) / 256, 256, 0, stream>>>(pmax, psum, cnt, (float*)d_out);
}

// Round 3
// 1292.308 us; speedup vs baseline: 7.7892x; 1.3624x over previous
//
#include <hip/hip_runtime.h>

#define HEADS 4

// ---- monotonic float <-> uint mapping for atomicMax on floats ----
__device__ __forceinline__ unsigned fmap(float f) {
  unsigned u = __float_as_uint(f);
  return (u & 0x80000000u) ? ~u : (u | 0x80000000u);
}
__device__ __forceinline__ float funmap(unsigned m) {
  unsigned u = (m & 0x80000000u) ? (m ^ 0x80000000u) : ~m;
  return __uint_as_float(u);
}

// ---------- node GEMM: Y[N,M] = X[N,K] @ W[K,M] + b ----------
template <int K, int M>
__global__ __launch_bounds__(256) void node_gemm(
    const float* __restrict__ X, const float* __restrict__ W,
    const float* __restrict__ bias, float* __restrict__ Y) {
  constexpr int NPB = 16;           // nodes per block (20000 % 16 == 0)
  constexpr int COLS4 = M / 4;      // 64 or 128
  constexpr int NG = 256 / COLS4;   // node groups per block: 4 or 2
  constexpr int RPN = NPB / NG;     // rows per thread: 4 or 8
  __shared__ float xs[NPB * K];
  const int tid = threadIdx.x;
  const int n0 = blockIdx.x * NPB;
  {
    const float4* X4 = reinterpret_cast<const float4*>(X + (size_t)n0 * K);
    float4* xs4 = reinterpret_cast<float4*>(xs);
    for (int i = tid; i < NPB * K / 4; i += 256) xs4[i] = X4[i];
  }
  __syncthreads();
  const int c4 = (tid % COLS4) * 4;
  const int r0 = (tid / COLS4) * RPN;
  float acc[RPN][4];
#pragma unroll
  for (int r = 0; r < RPN; ++r)
#pragma unroll
    for (int q = 0; q < 4; ++q) acc[r][q] = 0.f;

  for (int k = 0; k < K; k += 4) {
    float xv[RPN][4];
#pragma unroll
    for (int r = 0; r < RPN; ++r)
      *reinterpret_cast<float4*>(xv[r]) =
          *reinterpret_cast<const float4*>(&xs[(r0 + r) * K + k]);
#pragma unroll
    for (int j = 0; j < 4; ++j) {
      float wv[4];
      *reinterpret_cast<float4*>(wv) =
          *reinterpret_cast<const float4*>(&W[(size_t)(k + j) * M + c4]);
#pragma unroll
      for (int r = 0; r < RPN; ++r)
#pragma unroll
        for (int q = 0; q < 4; ++q)
          acc[r][q] = fmaf(xv[r][j], wv[q], acc[r][q]);
    }
  }
  float bv[4];
  *reinterpret_cast<float4*>(bv) = *reinterpret_cast<const float4*>(&bias[c4]);
#pragma unroll
  for (int r = 0; r < RPN; ++r) {
    float o[4];
#pragma unroll
    for (int q = 0; q < 4; ++q) o[q] = acc[r][q] + bv[q];
    *reinterpret_cast<float4*>(&Y[(size_t)(n0 + r0 + r) * M + c4]) =
        *reinterpret_cast<float4*>(o);
  }
}

// ---------- CSR build ----------
__global__ void edge_hist(const int* __restrict__ ei, int* __restrict__ deg, int E) {
  int i = blockIdx.x * blockDim.x + threadIdx.x;
  if (i < E) atomicAdd(&deg[ei[E + i]], 1);
}

__global__ __launch_bounds__(1024) void scan_rowptr(const int* __restrict__ deg,
                                                    int* __restrict__ rowptr, int N) {
  __shared__ int buf[1024];
  __shared__ int carry_s;
  const int tid = threadIdx.x;
  if (tid == 0) { carry_s = 0; rowptr[0] = 0; }
  __syncthreads();
  for (int base = 0; base < N; base += 1024) {
    int v = (base + tid < N) ? deg[base + tid] : 0;
    buf[tid] = v;
    __syncthreads();
    for (int off = 1; off < 1024; off <<= 1) {
      int t = (tid >= off) ? buf[tid - off] : 0;
      __syncthreads();
      buf[tid] += t;
      __syncthreads();
    }
    if (base + tid < N) rowptr[base + tid + 1] = carry_s + buf[tid];
    __syncthreads();
    if (tid == 0) carry_s += buf[1023];
    __syncthreads();
  }
}

__global__ void csr_fill(const int* __restrict__ ei, const int* __restrict__ rowptr,
                         int* __restrict__ fillc, int* __restrict__ csr_src,
                         int* __restrict__ csr_eid, int E) {
  int i = blockIdx.x * blockDim.x + threadIdx.x;
  if (i < E) {
    int d = ei[E + i];
    int pos = rowptr[d] + atomicAdd(&fillc[d], 1);
    csr_src[pos] = ei[i];
    csr_eid[pos] = i;
  }
}

// ---------- fused per-dst GATv2: single-pass online softmax + aggregate ----------
// One wave owns (dst, 256-column group). Each gathered xl row is used for BOTH
// the logit and the aggregation (one gather per edge). Two edges in flight.
template <int HC, bool CONCAT>
__global__ __launch_bounds__(256) void fused_gat(
    const float* __restrict__ xl, const float* __restrict__ xr,
    const float* __restrict__ ea, const float* __restrict__ We,
    const float* __restrict__ att, const float* __restrict__ bias,
    const int* __restrict__ rowptr, const int* __restrict__ csr_src,
    const int* __restrict__ csr_eid, float* __restrict__ out, int N) {
  constexpr int WPD = HC / 256;  // waves per dst
  constexpr int NH = 4 / WPD;    // heads handled by this wave
  constexpr int GS = 64 / NH;    // lanes per head group (16 or 32)
  constexpr int C = HC / 4;      // per-head dim
  const int lane = threadIdx.x & 63;
  const int wslot = threadIdx.x >> 6;
  const int gw = blockIdx.x * 4 + wslot;
  const int dst = gw / WPD;
  const int cg = gw % WPD;
  if (dst >= N) return;

  // We fragment in registers: wef[k][q] = We[k][cg*256 + lane*4 + q]
  float wef[16][4];
#pragma unroll
  for (int k = 0; k < 16; ++k)
    *reinterpret_cast<float4*>(wef[k]) =
        *reinterpret_cast<const float4*>(&We[k * HC + cg * 256 + lane * 4]);
  const int col0 = cg * 256 + lane * 4;
  const int head = col0 / C;
  float attv[4];
  *reinterpret_cast<float4*>(attv) =
      *reinterpret_cast<const float4*>(&att[head * C + (col0 % C)]);
  const float4* xl4 = reinterpret_cast<const float4*>(xl);
  const size_t coff = (size_t)cg * 64 + lane;
  const float4 xrv = reinterpret_cast<const float4*>(xr)[(size_t)dst * (HC / 4) + coff];
  const int l15 = lane & 15;

  const int row0 = rowptr[dst];
  const int deg = rowptr[dst + 1] - row0;

  float m = -__builtin_inff(), s = 0.f;
  float acc[4] = {0.f, 0.f, 0.f, 0.f};

  for (int cs = 0; cs < deg; cs += 64) {
    const int cn = min(64, deg - cs);
    const int srcv = (lane < cn) ? csr_src[row0 + cs + lane] : 0;
    const int eidv = (lane < cn) ? csr_eid[row0 + cs + lane] : 0;

    // prime the 2-edge pipeline
    const int i1 = (cn > 1) ? 1 : 0;
    int sA = __shfl(srcv, 0), eA = __shfl(eidv, 0);
    int sB = __shfl(srcv, i1), eB = __shfl(eidv, i1);
    float4 a0 = xl4[(size_t)sA * (HC / 4) + coff];
    float ev0 = ea[(size_t)eA * 16 + l15];
    float4 a1 = xl4[(size_t)sB * (HC / 4) + coff];
    float ev1 = ea[(size_t)eB * 16 + l15];

    for (int j = 0; j < cn; j += 2) {
      // prefetch edges j+2, j+3 (clamped; discarded past end)
      const int pA = min(j + 2, cn - 1), pB = min(j + 3, cn - 1);
      const int snA = __shfl(srcv, pA), enA = __shfl(eidv, pA);
      const int snB = __shfl(srcv, pB), enB = __shfl(eidv, pB);
      const float4 anA = xl4[(size_t)snA * (HC / 4) + coff];
      const float evnA = ea[(size_t)enA * 16 + l15];
      const float4 anB = xl4[(size_t)snB * (HC / 4) + coff];
      const float evnB = ea[(size_t)enB * 16 + l15];

      // ---- two independent logit chains ----
      float mv0[4] = {a0.x + xrv.x, a0.y + xrv.y, a0.z + xrv.z, a0.w + xrv.w};
      float mv1[4] = {a1.x + xrv.x, a1.y + xrv.y, a1.z + xrv.z, a1.w + xrv.w};
#pragma unroll
      for (int k = 0; k < 16; ++k) {
        const float c0 = __shfl(ev0, k);
        const float c1 = __shfl(ev1, k);
#pragma unroll
        for (int q = 0; q < 4; ++q) {
          mv0[q] = fmaf(c0, wef[k][q], mv0[q]);
          mv1[q] = fmaf(c1, wef[k][q], mv1[q]);
        }
      }
      float l0 = 0.f, l1 = 0.f;
#pragma unroll
      for (int q = 0; q < 4; ++q) {
        const float v0 = fmaxf(mv0[q], 0.2f * mv0[q]);  // leaky-relu
        const float v1 = fmaxf(mv1[q], 0.2f * mv1[q]);
        l0 = fmaf(v0, attv[q], l0);
        l1 = fmaf(v1, attv[q], l1);
      }
#pragma unroll
      for (int off = 1; off < GS; off <<= 1) {
        l0 += __shfl_xor(l0, off);
        l1 += __shfl_xor(l1, off);
      }

      // ---- online softmax update, edge j ----
      {
        const float nm = fmaxf(m, l0);
        const float sc = __expf(m - nm);  // ==1 when max unchanged
        const float pe = __expf(l0 - nm);
        m = nm;
        s = fmaf(s, sc, pe);
        acc[0] = fmaf(pe, a0.x, acc[0] * sc);
        acc[1] = fmaf(pe, a0.y, acc[1] * sc);
        acc[2] = fmaf(pe, a0.z, acc[2] * sc);
        acc[3] = fmaf(pe, a0.w, acc[3] * sc);
      }
      // ---- edge j+1 (uniform guard) ----
      if (j + 1 < cn) {
        const float nm = fmaxf(m, l1);
        const float sc = __expf(m - nm);
        const float pe = __expf(l1 - nm);
        m = nm;
        s = fmaf(s, sc, pe);
        acc[0] = fmaf(pe, a1.x, acc[0] * sc);
        acc[1] = fmaf(pe, a1.y, acc[1] * sc);
        acc[2] = fmaf(pe, a1.z, acc[2] * sc);
        acc[3] = fmaf(pe, a1.w, acc[3] * sc);
      }
      a0 = anA; ev0 = evnA;
      a1 = anB; ev1 = evnB;
    }
  }

  const float inv = 1.f / (s + 1e-16f);
  float o[4];
  if (CONCAT) {
    float bv[4];
    *reinterpret_cast<float4*>(bv) = *reinterpret_cast<const float4*>(&bias[col0]);
#pragma unroll
    for (int q = 0; q < 4; ++q) o[q] = acc[q] * inv + bv[q];
  } else {
#pragma unroll
    for (int q = 0; q < 4; ++q) o[q] = acc[q] * inv;
  }
  *reinterpret_cast<float4*>(&out[(size_t)dst * HC + col0]) =
      *reinterpret_cast<float4*>(o);
}

// ---------- layer-2 epilogue: mean over heads + bias ----------
__global__ void mean_heads(const float* __restrict__ acc, const float* __restrict__ bias,
                           float* __restrict__ out, int N) {
  int idx = blockIdx.x * blockDim.x + threadIdx.x;
  if (idx >= N * 128) return;
  int n = idx >> 7, c = idx & 127;
  const float* a = acc + (size_t)n * 512;
  out[idx] = 0.25f * (a[c] + a[128 + c] + a[256 + c] + a[384 + c]) + bias[c];
}

// ---------- pooling ----------
__global__ void pool_scatter(const float* __restrict__ h, const int* __restrict__ batch,
                             unsigned* __restrict__ pmax, float* __restrict__ psum,
                             float* __restrict__ cnt, int N) {
  int idx = blockIdx.x * blockDim.x + threadIdx.x;
  if (idx >= N * 128) return;
  int n = idx >> 7, c = idx & 127;
  int g = batch[n];
  float v = h[idx];
  atomicMax(&pmax[g * 128 + c], fmap(v));
  atomicAdd(&psum[g * 128 + c], v);
  if (c == 0) atomicAdd(&cnt[g], 1.f);
}

__global__ void pool_final(const unsigned* __restrict__ pmax, const float* __restrict__ psum,
                           const float* __restrict__ cnt, float* __restrict__ out) {
  int idx = blockIdx.x * blockDim.x + threadIdx.x;
  if (idx >= 64 * 128) return;
  int g = idx >> 7, c = idx & 127;
  float cg = cnt[g];
  out[g * 256 + c] = (cg > 0.f) ? funmap(pmax[idx]) : 0.f;
  out[g * 256 + 128 + c] = psum[idx] / fmaxf(cg, 1.f);
}

extern "C" void kernel_launch(void* const* d_in, const int* in_sizes, int n_in,
                              void* d_out, int out_size, void* d_ws, size_t ws_size,
                              hipStream_t stream) {
  const float* x     = (const float*)d_in[0];
  const float* ea    = (const float*)d_in[1];
  const int*   ei    = (const int*)d_in[2];
  const int*   batch = (const int*)d_in[3];
  const int N = in_sizes[0] / 128;  // 20000
  const int E = in_sizes[2] / 2;    // 640000

  const float* Wl[3]   = {(const float*)d_in[4],  (const float*)d_in[11], (const float*)d_in[18]};
  const float* blv[3]  = {(const float*)d_in[5],  (const float*)d_in[12], (const float*)d_in[19]};
  const float* Wr[3]   = {(const float*)d_in[6],  (const float*)d_in[13], (const float*)d_in[20]};
  const float* brv[3]  = {(const float*)d_in[7],  (const float*)d_in[14], (const float*)d_in[21]};
  const float* Wev[3]  = {(const float*)d_in[8],  (const float*)d_in[15], (const float*)d_in[22]};
  const float* attv[3] = {(const float*)d_in[9],  (const float*)d_in[16], (const float*)d_in[23]};
  const float* bias[3] = {(const float*)d_in[10], (const float*)d_in[17], (const float*)d_in[24]};

  // workspace layout
  float* ws = (float*)d_ws;
  float* xl   = ws;                            // N*512
  float* xr   = xl + (size_t)N * 512;          // N*512
  float* accb = xr + (size_t)N * 512;          // N*512 (layer-2 pre-mean)
  float* h    = accb + (size_t)N * 512;        // N*256
  int* rowptr = (int*)(h + (size_t)N * 256);   // N+1
  int* deg    = rowptr + (N + 1);              // N
  int* fillc  = deg + N;                       // N
  int* csr_src = fillc + N;                    // E
  int* csr_eid = csr_src + E;                  // E
  unsigned* pmax = (unsigned*)(csr_eid + E);   // 64*128
  float* psum = (float*)(pmax + 64 * 128);     // 64*128
  float* cnt  = psum + 64 * 128;               // 64
  (void)n_in; (void)out_size; (void)ws_size;

  const int nodeBlocks = N / 16;       // 1250
  const int edgeBlocks = (E + 255) / 256;

  // ---- CSR build (by destination) ----
  hipMemsetAsync(deg, 0, (size_t)2 * N * sizeof(int), stream);  // deg + fillc
  edge_hist<<<edgeBlocks, 256, 0, stream>>>(ei, deg, E);
  scan_rowptr<<<1, 1024, 0, stream>>>(deg, rowptr, N);
  csr_fill<<<edgeBlocks, 256, 0, stream>>>(ei, rowptr, fillc, csr_src, csr_eid, E);

  // ================= layer 0 (K=128 -> hc=256, concat) =================
  node_gemm<128, 256><<<nodeBlocks, 256, 0, stream>>>(x, Wl[0], blv[0], xl);
  node_gemm<128, 256><<<nodeBlocks, 256, 0, stream>>>(x, Wr[0], brv[0], xr);
  fused_gat<256, true><<<N / 4, 256, 0, stream>>>(
      xl, xr, ea, Wev[0], attv[0], bias[0], rowptr, csr_src, csr_eid, h, N);

  // ================= layer 1 (K=256 -> hc=256, concat) =================
  node_gemm<256, 256><<<nodeBlocks, 256, 0, stream>>>(h, Wl[1], blv[1], xl);
  node_gemm<256, 256><<<nodeBlocks, 256, 0, stream>>>(h, Wr[1], brv[1], xr);
  fused_gat<256, true><<<N / 4, 256, 0, stream>>>(
      xl, xr, ea, Wev[1], attv[1], bias[1], rowptr, csr_src, csr_eid, h, N);

  // ================= layer 2 (K=256 -> hc=512, mean over heads) =================
  node_gemm<256, 512><<<nodeBlocks, 256, 0, stream>>>(h, Wl[2], blv[2], xl);
  node_gemm<256, 512><<<nodeBlocks, 256, 0, stream>>>(h, Wr[2], brv[2], xr);
  fused_gat<512, false><<<N / 2, 256, 0, stream>>>(
      xl, xr, ea, Wev[2], attv[2], bias[2], rowptr, csr_src, csr_eid, accb, N);
  mean_heads<<<(N * 128 + 255) / 256, 256, 0, stream>>>(accb, bias[2], h, N);

  // ================= pooling =================
  hipMemsetAsync(pmax, 0, (size_t)(64 * 128 * 2 + 64) * sizeof(float), stream);
  pool_scatter<<<(N * 128 + 255) / 256, 256, 0, stream>>>(h, batch, pmax, psum, cnt, N);
  pool_final<<<(64 * 128 + 255) / 256, 256, 0, stream>>>(pmax, psum, cnt, (float*)d_out);
}